// Round 4
// baseline (927.659 us; speedup 1.0000x reference)
//
#include <hip/hip_runtime.h>
#include <hip/hip_bf16.h>

// Problem: x (16,256,32,32) fp32, weight (8193,256) fp32 (emb = first 8192 rows).
// Rows: r = b*1024 + (h*32+w), xf[r][c] = x[b*262144 + c*1024 + (r&1023)].
// Outputs (flat fp32): xq (4194304) | loss (1) | code-as-float (16384).
//
// R13: R12 (A resident in 128KB LDS) forced 1 block/CU: every phase serialized
// {LDS latency+throughput + MFMA + vmcnt(0) + barrier} with no co-resident work
// to hide any of it -> 96us vs a ~20-29us LDS-traffic floor. Fix: A needs L2
// residency, not LDS residency (R12 proved FETCH collapses when bx is fixed).
// Stream BOTH A and B chunks through a 4x16KB LDS dbuf (64KB total) -> 2
// blocks/CU; one block's MFMA/ds_reads hide the other's vmcnt/barrier stalls.
// Grid 512 persistent blocks: xcd=p&7, bx=xcd*4+(u&3) (per-XCD A set = 512KB,
// L2-resident), byg=u>>2, sweeps by=byg*4+s (per-XCD B set ~2MB). Same 8-phase
// BK=32 schedule, stage-issue at phase top (cover = ds_reads+MFMA), register-
// only top-2 epilogue. k_prep/k_out unchanged from R12 (same swizzled layout).

#define N_ROWS   16384
#define KCODES   8192
#define DIM      256
#define LOSS_OFF 4194304
#define CODE_OFF 4194305
#define MARGIN_ACC 0.006f          // covers f16 noise (~8e-4 rms) + 4.9e-4 idx-mask quant

typedef _Float16 half8  __attribute__((ext_vector_type(8)));
typedef _Float16 half4v __attribute__((ext_vector_type(4)));
typedef float    float4v __attribute__((ext_vector_type(4)));
typedef float    float2v __attribute__((ext_vector_type(2)));
typedef unsigned long long u64;

__device__ __forceinline__ unsigned umax32(unsigned a, unsigned b) { return a > b ? a : b; }
__device__ __forceinline__ unsigned umin32(unsigned a, unsigned b) { return a < b ? a : b; }
__device__ __forceinline__ void gll16(const _Float16* g, _Float16* l) {
  __builtin_amdgcn_global_load_lds((const __attribute__((address_space(1))) void*)g,
                                   (__attribute__((address_space(3))) void*)l, 16, 0, 0);
}

// Swizzled tile layout (xh and eh): per 128-row tile: [8 granules of 32 halves],
// granule = 4096 halves (8 KB contiguous). Within granule: row rl (0..127) at
// rl*32, unit kgp (0..3, 8 halves) stores source k-group kgp ^ ((rl>>1)&3).

// ---------------------------------------------------------------- fused prep (+ Sxx partials)
__global__ __launch_bounds__(256) void k_prep(const float* __restrict__ x, _Float16* __restrict__ xh,
                                              const float* __restrict__ wt, _Float16* __restrict__ eh,
                                              float* __restrict__ en2c, float* __restrict__ sxxp,
                                              double* __restrict__ dacc, unsigned* __restrict__ cnt) {
  __shared__ float lsx[128 * 65];               // x path: [n][c'] fp32, stride 65
  __shared__ __align__(16) _Float16 ls[8192];   // e path: 32 codes x 256 halves
  __shared__ float es[32];
  int t = threadIdx.x;
  int lane = t & 63, wv = t >> 6;
  int bid = blockIdx.x;
  if (bid < 512) {
    // ---- x path: 512 blocks = 128 row-tiles x 4 channel-quarters (64 ch each)
    if (bid == 0 && t == 0) { dacc[0] = 0.0; *cnt = 0u; }   // consumed only in k_out
    int blk = bid >> 2, cc = bid & 3;
    int row0 = blk * 128;
    int b    = row0 >> 10;
    int n0   = row0 & 1023;
    const float* xb = x + (size_t)b * 262144 + n0;   // xb[c*1024 + n_local]
    int c_off = t >> 6;                              // 0..3 (one c per wave per j)
    int nn    = (t & 63) * 2;                        // 0..126
    float sxx = 0.f;
    for (int j = 0; j < 16; ++j) {
      int c = cc * 64 + j * 4 + c_off;
      float2v v = *(const float2v*)&xb[(size_t)c * 1024 + nn];   // wave: 512B contiguous
      int cp = c & 63;
      sxx = fmaf(v[0], v[0], sxx);
      sxx = fmaf(v[1], v[1], sxx);
      lsx[nn * 65 + cp]       = v[0];               // 2-way bank alias (free)
      lsx[(nn + 1) * 65 + cp] = v[1];
    }
    __syncthreads();
#pragma unroll
    for (int i = 0; i < 4; ++i) {                    // 1024 units = 128 rows x 8
      int unit = i * 256 + t;
      int rl = unit >> 3, pp = unit & 7;
      int chl = pp >> 2, kgp = pp & 3;               // granule-half, output k-group
      int kg  = kgp ^ ((rl >> 1) & 3);               // source k-group
      const float* src = &lsx[rl * 65 + chl * 32 + kg * 8];
      half8 h;
#pragma unroll
      for (int k2 = 0; k2 < 8; ++k2) h[k2] = (_Float16)src[k2];
      *(half8*)&xh[(size_t)blk * 32768 + (size_t)(cc * 2 + chl) * 4096 + (size_t)rl * 32 + kgp * 8] = h;
    }
#pragma unroll
    for (int d = 32; d; d >>= 1) sxx += __shfl_xor(sxx, d);
    __syncthreads();
    if (lane == 0) lsx[wv] = sxx;
    __syncthreads();
    if (t == 0) sxxp[bid] = lsx[0] + lsx[1] + lsx[2] + lsx[3];
  } else {
    // ---- e path: 256 blocks x 32 codes (swizzled eh)
    int blk  = bid - 512;
    int k0 = blk * 32;
    const float* wb = wt + (size_t)k0 * 256;
    for (int i = 0; i < 8; ++i) {
      int lin = i * 1024 + t * 4;                 // all lanes of a wave share lin>>8 = i*4+wv
      float4v v = *(const float4v*)&wb[lin];
      half4v h; float ss = 0.f;
#pragma unroll
      for (int j = 0; j < 4; ++j) { h[j] = (_Float16)v[j]; ss = fmaf(v[j], v[j], ss); }
      *(half4v*)&ls[lin] = h;
#pragma unroll
      for (int d = 32; d; d >>= 1) ss += __shfl_xor(ss, d);
      if (lane == 0) es[i * 4 + wv] = ss;
    }
    __syncthreads();
    size_t tb = (size_t)(k0 >> 7) * 32768;
    for (int i = 0; i < 4; ++i) {
      int u = i * 256 + t;                        // 1024 units = 32 codes x 32
      int code_l = u >> 5;
      int cu = u & 31, ch = cu >> 2, kgp = cu & 3;
      int rl = (k0 + code_l) & 127;               // row within 128-code tile
      int kg = kgp ^ ((rl >> 1) & 3);
      half8 h = *(half8*)&ls[code_l * 256 + ch * 32 + kg * 8];
      *(half8*)&eh[tb + (size_t)ch * 4096 + (size_t)rl * 32 + kgp * 8] = h;
    }
    if (t < 32) en2c[k0 + t] = 32.0f - 0.5f * es[t];
  }
}

// ---------------------------------------------------------------- main GEMM: streamed A+B, 2 blocks/CU [R13]
__global__ __launch_bounds__(512, 4) void k_gemm(const _Float16* __restrict__ xh, const _Float16* __restrict__ eh,
                                                 const float* __restrict__ en2c,
                                                 u64* __restrict__ top2) {
  __shared__ __align__(16) _Float16 Ab[2][8192];    // dbuf: A chunk (256 codes x 32 Kh = 16 KB)
  __shared__ __align__(16) _Float16 Bb[2][8192];    // dbuf: B chunk (256 rows  x 32 Kh = 16 KB)
  int t    = threadIdx.x;
  int lane = t & 63, w = t >> 6;
  int wr = w >> 2, wc = w & 3;                  // wave: codes 128*wr, xrows 64*wc
  int ln15 = lane & 15, q = (lane >> 4) & 3;
  int q4 = q * 4;

  int p   = (int)blockIdx.x;                    // 512 blocks = 2/CU
  int xcd = p & 7;                              // dispatch round-robins XCDs
  int u   = p >> 3;                             // 0..63
  int bx  = xcd * 4 + (u & 3);                  // per-XCD A set = 4 panels (512 KB, L2)
  int byg = u >> 2;                             // 0..15; block sweeps by = byg*4+s

  const _Float16* Ae = eh + (size_t)bx * 65536; // 2 adjacent 128-code tiles, contiguous
  const float*    cb = &en2c[bx * 256 + wr * 128 + q4];

  float4v acc[8][4];

  // prologue: stage (s=0, chunk 0) A+B into buf 0; drain once
  {
    const _Float16* B0 = xh + (size_t)(byg * 4) * 65536;
    gll16(Ae + t * 8,         &Ab[0][0]    + w * 512);
    gll16(Ae + 32768 + t * 8, &Ab[0][4096] + w * 512);
    gll16(B0 + t * 8,         &Bb[0][0]    + w * 512);
    gll16(B0 + 32768 + t * 8, &Bb[0][4096] + w * 512);
  }
  asm volatile("s_waitcnt vmcnt(0)" ::: "memory");
  __builtin_amdgcn_s_barrier();

#pragma unroll 1
  for (int s = 0; s < 4; ++s) {
    int by = byg * 4 + s;
    const _Float16* Bt = xh + (size_t)by * 65536;   // this tile's B (2 row-tiles)
#pragma unroll
    for (int mi = 0; mi < 8; ++mi) {
      float4v cin = *(const float4v*)&cb[mi * 16];
#pragma unroll
      for (int ni = 0; ni < 4; ++ni) acc[mi][ni] = cin;
    }
#pragma unroll
    for (int c = 0; c < 8; ++c) {
      // ---- stage NEXT chunk at phase top (max vmcnt cover: ds_reads + MFMA).
      // Write-safe: buf (c+1)&1 was read in phase c-1; those reads retired at
      // phase c-1's lgkmcnt(0) before its barrier, which all waves passed.
      if (c < 7) {
        _Float16* An = &Ab[(c + 1) & 1][0];
        _Float16* Bn = &Bb[(c + 1) & 1][0];
        gll16(Ae + (c + 1) * 4096 + t * 8,         An        + w * 512);
        gll16(Ae + 32768 + (c + 1) * 4096 + t * 8, An + 4096 + w * 512);
        gll16(Bt + (c + 1) * 4096 + t * 8,         Bn        + w * 512);
        gll16(Bt + 32768 + (c + 1) * 4096 + t * 8, Bn + 4096 + w * 512);
      } else if (s < 3) {                          // chunk 0 of next s-tile -> buf 0
        const _Float16* Bn2 = Bt + 65536;
        gll16(Ae + t * 8,          &Ab[0][0]    + w * 512);
        gll16(Ae + 32768 + t * 8,  &Ab[0][4096] + w * 512);
        gll16(Bn2 + t * 8,         &Bb[0][0]    + w * 512);
        gll16(Bn2 + 32768 + t * 8, &Bb[0][4096] + w * 512);
      }
      // ---- ds_read frags from the landed chunk
      half8 af[8], bf[4];
#pragma unroll
      for (int mi = 0; mi < 8; ++mi) {
        int rl = mi * 16 + ln15;
        af[mi] = *(const half8*)&Ab[c & 1][wr * 4096 + rl * 32 + ((q ^ ((rl >> 1) & 3)) * 8)];
      }
#pragma unroll
      for (int ni = 0; ni < 4; ++ni) {
        int rb = (wc & 1) * 64 + ni * 16 + ln15;
        bf[ni] = *(const half8*)&Bb[c & 1][(wc >> 1) * 4096 + rb * 32 + ((q ^ ((rb >> 1) & 3)) * 8)];
      }
      asm volatile("s_waitcnt lgkmcnt(0)");
      __builtin_amdgcn_sched_barrier(0);
      __builtin_amdgcn_s_setprio(1);
#pragma unroll
      for (int mi = 0; mi < 8; ++mi)
#pragma unroll
        for (int ni = 0; ni < 4; ++ni)
          acc[mi][ni] = __builtin_amdgcn_mfma_f32_16x16x32_f16(af[mi], bf[ni], acc[mi][ni], 0, 0, 0);
      __builtin_amdgcn_s_setprio(0);
      asm volatile("s_waitcnt vmcnt(0)" ::: "memory");  // next chunk landed (hidden under this phase)
      __builtin_amdgcn_s_barrier();
    }

    // ---- epilogue (register-only, no LDS): per x-row top-2 over this wave's
    // 128 codes -> direct global write. Runs after phase 7's barrier; next
    // s-tile's phase 0 needs only buf 0 (already landed) and its own barrier.
#pragma unroll
    for (int ni = 0; ni < 4; ++ni) {
      unsigned hi[16], lo2[16];
#pragma unroll
      for (int mi = 0; mi < 8; ++mi)
#pragma unroll
        for (int rb = 0; rb < 4; rb += 2) {
          int jj = mi * 2 + (rb >> 1);
          unsigned p0 = (__float_as_uint(acc[mi][ni][rb])     & 0xFFFFFF80u) | (unsigned)(mi * 16 + q4 + rb);
          unsigned p1 = (__float_as_uint(acc[mi][ni][rb + 1]) & 0xFFFFFF80u) | (unsigned)(mi * 16 + q4 + rb + 1);
          hi[jj] = umax32(p0, p1); lo2[jj] = umin32(p0, p1);
        }
#pragma unroll
      for (int st = 8; st; st >>= 1)
#pragma unroll
        for (int jj = 0; jj < 8; ++jj) if (jj < st) {
          unsigned nb = umax32(hi[jj], hi[jj + st]);
          unsigned ns = umax32(umin32(hi[jj], hi[jj + st]), umax32(lo2[jj], lo2[jj + st]));
          hi[jj] = nb; lo2[jj] = ns;
        }
      unsigned b = hi[0], sv = lo2[0];
#pragma unroll
      for (int dd = 16; dd < 64; dd <<= 1) {
        unsigned ob = __shfl_xor(b, dd);
        unsigned os = __shfl_xor(sv, dd);
        unsigned ns = umax32(umin32(b, ob), umax32(sv, os));
        b = umax32(b, ob); sv = ns;
      }
      if (q == 0) {
        int row = by * 256 + wc * 64 + ni * 16 + ln15;
        top2[(size_t)(bx * 2 + wr) * 16384 + row] = ((u64)b << 32) | sv;
      }
    }
  }
}

// ---------------------------------------------------------------- fused refine + gather + loss
__global__ __launch_bounds__(1024) void k_out(const u64* __restrict__ top2,
                                              const float* __restrict__ x, const float* __restrict__ w,
                                              float* __restrict__ out, const float* __restrict__ sxxp,
                                              double* __restrict__ dacc, unsigned* __restrict__ cnt) {
  __shared__ float ect[256 * 65];      // [c][r] transposed, stride 65; both phases <=2-way
  __shared__ double dpart[16];
  __shared__ unsigned oldc;
  int t    = threadIdx.x;
  int lane = t & 63, wv = t >> 6;      // 16 waves
  int blk  = blockIdx.x;               // 256 blocks x 64 rows
  int row0 = blk * 64;
  int b = row0 >> 10, n0 = row0 & 1023;

  // ---- phase 1: refine + inline gather + score contribution, 4 rows per wave
  double dsum = 0.0;
  for (int j = 0; j < 4; ++j) {
    int rl  = wv * 4 + j;
    int row = row0 + rl;
    u64 e = top2[(size_t)lane * 16384 + row];    // lane = code-tile
    unsigned hi = (unsigned)(e >> 32), lo = (unsigned)e;
    unsigned mx = hi;
#pragma unroll
    for (int d = 1; d < 64; d <<= 1) mx = umax32(mx, __shfl_xor(mx, d));
    float fm = __uint_as_float(mx & 0xFFFFFF80u);
    float th = fm - MARGIN_ACC;
    bool c0 = __uint_as_float(hi & 0xFFFFFF80u) >= th;
    bool c1 = __uint_as_float(lo & 0xFFFFFF80u) >= th;
    u64 bal0 = __ballot(c0), bal1 = __ballot(c1);
    int kbest;
    double d2c;                                  // = ||e||^2 - 2 x.e for the chosen code
    if (__popcll(bal0) + __popcll(bal1) <= 1) {
      int l0 = __ffsll((unsigned long long)__ballot(hi == mx)) - 1;
      kbest = l0 * 128 + (int)(__shfl(hi, l0) & 127u);
      d2c = 64.0 - 2.0 * (double)fm;             // quantized acc: +4.9e-4 worst-case per row
    } else {
      const float* xr = x + (size_t)b * 262144 + (row & 1023);
      float4v ex;
#pragma unroll
      for (int i = 0; i < 4; ++i) ex[i] = xr[(size_t)(lane * 4 + i) * 1024];
      double bs = 1e300; int bk = 0x7fffffff;
      for (int pass = 0; pass < 2; ++pass) {
        u64 bal = pass ? bal1 : bal0;
        unsigned src = pass ? lo : hi;
        while (bal) {
          int l = __ffsll((unsigned long long)bal) - 1;
          bal &= bal - 1;
          int kc = l * 128 + (int)(__shfl(src, l) & 127u);
          float4v wv4 = *(const float4v*)&w[(size_t)kc * DIM + lane * 4];
          double s = 0.0;
#pragma unroll
          for (int i = 0; i < 4; ++i) { double ev = (double)wv4[i]; s += ev * (ev - 2.0 * (double)ex[i]); }
#pragma unroll
          for (int d = 1; d < 64; d <<= 1) s += __shfl_xor(s, d);
          if (s < bs || (s == bs && kc < bk)) { bs = s; bk = kc; }
        }
      }
      kbest = bk;                                // all lanes agree (shuffle-reduced)
      d2c = bs;                                  // exact fp64
    }
    if (lane == 0) { out[CODE_OFF + row] = (float)kbest; dsum += d2c; }
    // inline gather: whole wave loads this row's e-vector (coalesced 256B x4)
    const float* wrow = w + (size_t)kbest * 256;
#pragma unroll
    for (int i = 0; i < 4; ++i) ect[(i * 64 + lane) * 65 + rl] = wrow[i * 64 + lane];
  }
  __syncthreads();

  // ---- phase 2: write xq (full-wave 256B txns); loss from scores, no x read
  const size_t base = (size_t)b * 262144 + n0 + lane;
  for (int j = 0; j < 16; ++j) {
    int c = wv * 16 + j;
    out[base + (size_t)c * 1024] = ect[c * 65 + lane];
  }
  if (lane == 0) dpart[wv] = dsum;
  __syncthreads();
  if (t == 0) {
    double s = 0.0;
#pragma unroll
    for (int i = 0; i < 16; ++i) s += dpart[i];
    atomicAdd(&dacc[0], s);
    __threadfence();
    oldc = atomicAdd(cnt, 1u);
  }
  __syncthreads();
  if (oldc == 255u && t < 64) {                  // last block: wave 0 finalizes
    float ps = 0.f;
#pragma unroll
    for (int i = 0; i < 8; ++i) ps += sxxp[t * 8 + i];
#pragma unroll
    for (int d = 32; d; d >>= 1) ps += __shfl_xor(ps, d);
    if (t == 0) {
      __threadfence();
      double sd2 = *(volatile double*)&dacc[0];
      out[LOSS_OFF] = (float)(1.25 * ((double)ps + sd2) / 4194304.0);
    }
  }
}

// ---------------------------------------------------------------- launch
extern "C" void kernel_launch(void* const* d_in, const int* in_sizes, int n_in,
                              void* d_out, int out_size, void* d_ws, size_t ws_size,
                              hipStream_t stream) {
  const float* x = (const float*)d_in[0];
  const float* w = (const float*)d_in[1];
  float* out = (float*)d_out;
  char* ws = (char*)d_ws;
  _Float16* xh   = (_Float16*)(ws);                 //  8,388,608 B (swizzled tiles)
  _Float16* eh   = (_Float16*)(ws + 8388608);       //  4,194,304 B (swizzled tiles)
  float*    en2c = (float*)(ws + 12582912);         //     32,768 B
  u64*      top2 = (u64*)(ws + 12615680);           //  8,388,608 B ([64 tile][16384 row] u64)
  float*    sxxp = (float*)(ws + 21004288);         //      2,048 B (512 partials)
  double*   dacc = (double*)(ws + 21006336);        //          8 B (sum d2)
  unsigned* cnt  = (unsigned*)(ws + 21006344);      //          4 B

  k_prep<<<768, 256, 0, stream>>>(x, xh, w, eh, en2c, sxxp, dacc, cnt);
  k_gemm<<<512, 512, 0, stream>>>(xh, eh, en2c, top2);
  k_out<<<256, 1024, 0, stream>>>(top2, x, w, out, sxxp, dacc, cnt);
}

// Round 5
// 200.945 us; speedup vs baseline: 4.6165x; 4.6165x over previous
//
#include <hip/hip_runtime.h>
#include <hip/hip_bf16.h>

// Problem: x (16,256,32,32) fp32, weight (8193,256) fp32 (emb = first 8192 rows).
// Rows: r = b*1024 + (h*32+w), xf[r][c] = x[b*262144 + c*1024 + (r&1023)].
// Outputs (flat fp32): xq (4194304) | loss (1) | code-as-float (16384).
//
// R14: R13 spilled (launch_bounds(512,4) -> 64-VGPR cap vs 128-f32 acc ->
// 3.3GB scratch traffic). 2 blocks/CU is register-impossible for a 128x64
// per-wave tile; 1 block/CU is forced, so overlap must come from PIPELINING:
// counted vmcnt (T4), never drain in the main loop. Ring of 4 chunk buffers
// (A+B 32KB each, 128KB LDS, ring idx = c&3 compile-time). Phase g:
// {vmcnt(4) [waits chunk g, staged 2 phases ~2600cyc ago; chunk g+1 stays in
// flight across the barrier] -> s_barrier -> stage chunk g+2 -> ds_read
// buf[g&3] -> setprio(1) 32xMFMA setprio(0)}. One barrier/phase. Write-safe:
// buf[(g+2)&3] was last read in phase g-2, two barriers ago. launch_bounds
// (512,2) -> 256 VGPR cap, no spill. Grid 256 persistent (1/CU): bx=xcd*4+
// (u&3) (per-XCD A=512KB L2-resident), by=byg*8+s sweep (B inst. set ~1MB).
// Register-only top-2 epilogue per s-tile, stores ride the vmcnt ring.
// k_prep / k_out unchanged from R12 (same 32-half granule swizzled layout).

#define N_ROWS   16384
#define KCODES   8192
#define DIM      256
#define LOSS_OFF 4194304
#define CODE_OFF 4194305
#define MARGIN_ACC 0.006f          // covers f16 noise (~8e-4 rms) + 4.9e-4 idx-mask quant

typedef _Float16 half8  __attribute__((ext_vector_type(8)));
typedef _Float16 half4v __attribute__((ext_vector_type(4)));
typedef float    float4v __attribute__((ext_vector_type(4)));
typedef float    float2v __attribute__((ext_vector_type(2)));
typedef unsigned long long u64;

__device__ __forceinline__ unsigned umax32(unsigned a, unsigned b) { return a > b ? a : b; }
__device__ __forceinline__ unsigned umin32(unsigned a, unsigned b) { return a < b ? a : b; }
__device__ __forceinline__ void gll16(const _Float16* g, _Float16* l) {
  __builtin_amdgcn_global_load_lds((const __attribute__((address_space(1))) void*)g,
                                   (__attribute__((address_space(3))) void*)l, 16, 0, 0);
}

// Swizzled tile layout (xh and eh): per 128-row tile: [8 granules of 32 halves],
// granule = 4096 halves (8 KB contiguous). Within granule: row rl (0..127) at
// rl*32, unit kgp (0..3, 8 halves) stores source k-group kgp ^ ((rl>>1)&3).

// ---------------------------------------------------------------- fused prep (+ Sxx partials)
__global__ __launch_bounds__(256) void k_prep(const float* __restrict__ x, _Float16* __restrict__ xh,
                                              const float* __restrict__ wt, _Float16* __restrict__ eh,
                                              float* __restrict__ en2c, float* __restrict__ sxxp,
                                              double* __restrict__ dacc, unsigned* __restrict__ cnt) {
  __shared__ float lsx[128 * 65];               // x path: [n][c'] fp32, stride 65
  __shared__ __align__(16) _Float16 ls[8192];   // e path: 32 codes x 256 halves
  __shared__ float es[32];
  int t = threadIdx.x;
  int lane = t & 63, wv = t >> 6;
  int bid = blockIdx.x;
  if (bid < 512) {
    // ---- x path: 512 blocks = 128 row-tiles x 4 channel-quarters (64 ch each)
    if (bid == 0 && t == 0) { dacc[0] = 0.0; *cnt = 0u; }   // consumed only in k_out
    int blk = bid >> 2, cc = bid & 3;
    int row0 = blk * 128;
    int b    = row0 >> 10;
    int n0   = row0 & 1023;
    const float* xb = x + (size_t)b * 262144 + n0;   // xb[c*1024 + n_local]
    int c_off = t >> 6;                              // 0..3 (one c per wave per j)
    int nn    = (t & 63) * 2;                        // 0..126
    float sxx = 0.f;
    for (int j = 0; j < 16; ++j) {
      int c = cc * 64 + j * 4 + c_off;
      float2v v = *(const float2v*)&xb[(size_t)c * 1024 + nn];   // wave: 512B contiguous
      int cp = c & 63;
      sxx = fmaf(v[0], v[0], sxx);
      sxx = fmaf(v[1], v[1], sxx);
      lsx[nn * 65 + cp]       = v[0];               // 2-way bank alias (free)
      lsx[(nn + 1) * 65 + cp] = v[1];
    }
    __syncthreads();
#pragma unroll
    for (int i = 0; i < 4; ++i) {                    // 1024 units = 128 rows x 8
      int unit = i * 256 + t;
      int rl = unit >> 3, pp = unit & 7;
      int chl = pp >> 2, kgp = pp & 3;               // granule-half, output k-group
      int kg  = kgp ^ ((rl >> 1) & 3);               // source k-group
      const float* src = &lsx[rl * 65 + chl * 32 + kg * 8];
      half8 h;
#pragma unroll
      for (int k2 = 0; k2 < 8; ++k2) h[k2] = (_Float16)src[k2];
      *(half8*)&xh[(size_t)blk * 32768 + (size_t)(cc * 2 + chl) * 4096 + (size_t)rl * 32 + kgp * 8] = h;
    }
#pragma unroll
    for (int d = 32; d; d >>= 1) sxx += __shfl_xor(sxx, d);
    __syncthreads();
    if (lane == 0) lsx[wv] = sxx;
    __syncthreads();
    if (t == 0) sxxp[bid] = lsx[0] + lsx[1] + lsx[2] + lsx[3];
  } else {
    // ---- e path: 256 blocks x 32 codes (swizzled eh)
    int blk  = bid - 512;
    int k0 = blk * 32;
    const float* wb = wt + (size_t)k0 * 256;
    for (int i = 0; i < 8; ++i) {
      int lin = i * 1024 + t * 4;                 // all lanes of a wave share lin>>8 = i*4+wv
      float4v v = *(const float4v*)&wb[lin];
      half4v h; float ss = 0.f;
#pragma unroll
      for (int j = 0; j < 4; ++j) { h[j] = (_Float16)v[j]; ss = fmaf(v[j], v[j], ss); }
      *(half4v*)&ls[lin] = h;
#pragma unroll
      for (int d = 32; d; d >>= 1) ss += __shfl_xor(ss, d);
      if (lane == 0) es[i * 4 + wv] = ss;
    }
    __syncthreads();
    size_t tb = (size_t)(k0 >> 7) * 32768;
    for (int i = 0; i < 4; ++i) {
      int u = i * 256 + t;                        // 1024 units = 32 codes x 32
      int code_l = u >> 5;
      int cu = u & 31, ch = cu >> 2, kgp = cu & 3;
      int rl = (k0 + code_l) & 127;               // row within 128-code tile
      int kg = kgp ^ ((rl >> 1) & 3);
      half8 h = *(half8*)&ls[code_l * 256 + ch * 32 + kg * 8];
      *(half8*)&eh[tb + (size_t)ch * 4096 + (size_t)rl * 32 + kgp * 8] = h;
    }
    if (t < 32) en2c[k0 + t] = 32.0f - 0.5f * es[t];
  }
}

// ---------------------------------------------------------------- main GEMM: ring-4 counted-vmcnt pipeline [R14]
__global__ __launch_bounds__(512, 2) void k_gemm(const _Float16* __restrict__ xh, const _Float16* __restrict__ eh,
                                                 const float* __restrict__ en2c,
                                                 u64* __restrict__ top2) {
  __shared__ __align__(16) _Float16 Ab[4][8192];    // ring: A chunk (256 codes x 32 Kh = 16 KB)
  __shared__ __align__(16) _Float16 Bb[4][8192];    // ring: B chunk (256 rows  x 32 Kh = 16 KB)
  int t    = threadIdx.x;
  int lane = t & 63, w = t >> 6;
  int wr = w >> 2, wc = w & 3;                  // wave: codes 128*wr, xrows 64*wc
  int ln15 = lane & 15, q = (lane >> 4) & 3;
  int q4 = q * 4;

  int p   = (int)blockIdx.x;                    // 256 blocks = 1/CU, persistent
  int xcd = p & 7;                              // dispatch round-robins XCDs
  int u   = p >> 3;                             // 0..31
  int bx  = xcd * 4 + (u & 3);                  // per-XCD A set = 4 panels (512 KB, L2)
  int byg = u >> 2;                             // 0..7; block sweeps by = byg*8+s

  const _Float16* Ae = eh + (size_t)bx * 65536; // 2 adjacent 128-code tiles, contiguous
  const float*    cb = &en2c[bx * 256 + wr * 128 + q4];

  // prologue: stage chunks 0,1 into ring slots 0,1 (B from s=0)
  {
    const _Float16* Bt0 = xh + (size_t)(byg * 8) * 65536;
    gll16(Ae + t * 8,                &Ab[0][0]    + w * 512);
    gll16(Ae + 32768 + t * 8,        &Ab[0][4096] + w * 512);
    gll16(Bt0 + t * 8,               &Bb[0][0]    + w * 512);
    gll16(Bt0 + 32768 + t * 8,       &Bb[0][4096] + w * 512);
    gll16(Ae + 4096 + t * 8,         &Ab[1][0]    + w * 512);
    gll16(Ae + 36864 + t * 8,        &Ab[1][4096] + w * 512);
    gll16(Bt0 + 4096 + t * 8,        &Bb[1][0]    + w * 512);
    gll16(Bt0 + 36864 + t * 8,       &Bb[1][4096] + w * 512);
  }

  float4v acc[8][4];
#pragma unroll 1
  for (int s = 0; s < 8; ++s) {
    int by = byg * 8 + s;
#pragma unroll
    for (int mi = 0; mi < 8; ++mi) {
      float4v cin = *(const float4v*)&cb[mi * 16];
#pragma unroll
      for (int ni = 0; ni < 4; ++ni) acc[mi][ni] = cin;
    }
#pragma unroll
    for (int c = 0; c < 8; ++c) {
      // ---- counted wait: chunk g (=s*8+c) landed; chunk g+1 stays in flight.
      // (own-wave vmcnt(4) + barrier => ALL waves' chunk-g loads landed)
      asm volatile("s_waitcnt vmcnt(4)" ::: "memory");
      __builtin_amdgcn_s_barrier();
      __builtin_amdgcn_sched_barrier(0);
      // ---- stage chunk g+2 into ring slot (c+2)&3 (held g-2's data: last
      // read in phase g-2, two barriers ago -> write-safe). Tail wraps to
      // chunk (g+2)&63 (harmless re-stage, never read).
      {
        const int c2 = (c + 2) & 7;
        int s2 = (c >= 6) ? ((s + 1) & 7) : s;
        const _Float16* Bt2 = xh + (size_t)(byg * 8 + s2) * 65536;
        _Float16* An = &Ab[(c + 2) & 3][0];
        _Float16* Bn = &Bb[(c + 2) & 3][0];
        gll16(Ae + c2 * 4096 + t * 8,          An        + w * 512);
        gll16(Ae + 32768 + c2 * 4096 + t * 8,  An + 4096 + w * 512);
        gll16(Bt2 + c2 * 4096 + t * 8,         Bn        + w * 512);
        gll16(Bt2 + 32768 + c2 * 4096 + t * 8, Bn + 4096 + w * 512);
      }
      // ---- ds_read frags from the landed chunk (compiler emits counted lgkm)
      half8 af[8], bf[4];
#pragma unroll
      for (int mi = 0; mi < 8; ++mi) {
        int rl = mi * 16 + ln15;
        af[mi] = *(const half8*)&Ab[c & 3][wr * 4096 + rl * 32 + ((q ^ ((rl >> 1) & 3)) * 8)];
      }
#pragma unroll
      for (int ni = 0; ni < 4; ++ni) {
        int rb = (wc & 1) * 64 + ni * 16 + ln15;
        bf[ni] = *(const half8*)&Bb[c & 3][(wc >> 1) * 4096 + rb * 32 + ((q ^ ((rb >> 1) & 3)) * 8)];
      }
      __builtin_amdgcn_s_setprio(1);
#pragma unroll
      for (int mi = 0; mi < 8; ++mi)
#pragma unroll
        for (int ni = 0; ni < 4; ++ni)
          acc[mi][ni] = __builtin_amdgcn_mfma_f32_16x16x32_f16(af[mi], bf[ni], acc[mi][ni], 0, 0, 0);
      __builtin_amdgcn_s_setprio(0);
    }

    // ---- epilogue (register-only, no LDS/barrier): per x-row top-2 over this
    // wave's 128 codes -> direct global write; stores ride the vmcnt ring.
#pragma unroll
    for (int ni = 0; ni < 4; ++ni) {
      unsigned hi[16], lo2[16];
#pragma unroll
      for (int mi = 0; mi < 8; ++mi)
#pragma unroll
        for (int rb = 0; rb < 4; rb += 2) {
          int jj = mi * 2 + (rb >> 1);
          unsigned p0 = (__float_as_uint(acc[mi][ni][rb])     & 0xFFFFFF80u) | (unsigned)(mi * 16 + q4 + rb);
          unsigned p1 = (__float_as_uint(acc[mi][ni][rb + 1]) & 0xFFFFFF80u) | (unsigned)(mi * 16 + q4 + rb + 1);
          hi[jj] = umax32(p0, p1); lo2[jj] = umin32(p0, p1);
        }
#pragma unroll
      for (int st = 8; st; st >>= 1)
#pragma unroll
        for (int jj = 0; jj < 8; ++jj) if (jj < st) {
          unsigned nb = umax32(hi[jj], hi[jj + st]);
          unsigned ns = umax32(umin32(hi[jj], hi[jj + st]), umax32(lo2[jj], lo2[jj + st]));
          hi[jj] = nb; lo2[jj] = ns;
        }
      unsigned b = hi[0], sv = lo2[0];
#pragma unroll
      for (int dd = 16; dd < 64; dd <<= 1) {
        unsigned ob = __shfl_xor(b, dd);
        unsigned os = __shfl_xor(sv, dd);
        unsigned ns = umax32(umin32(b, ob), umax32(sv, os));
        b = umax32(b, ob); sv = ns;
      }
      if (q == 0) {
        int row = by * 256 + wc * 64 + ni * 16 + ln15;
        top2[(size_t)(bx * 2 + wr) * 16384 + row] = ((u64)b << 32) | sv;
      }
    }
  }
}

// ---------------------------------------------------------------- fused refine + gather + loss
__global__ __launch_bounds__(1024) void k_out(const u64* __restrict__ top2,
                                              const float* __restrict__ x, const float* __restrict__ w,
                                              float* __restrict__ out, const float* __restrict__ sxxp,
                                              double* __restrict__ dacc, unsigned* __restrict__ cnt) {
  __shared__ float ect[256 * 65];      // [c][r] transposed, stride 65; both phases <=2-way
  __shared__ double dpart[16];
  __shared__ unsigned oldc;
  int t    = threadIdx.x;
  int lane = t & 63, wv = t >> 6;      // 16 waves
  int blk  = blockIdx.x;               // 256 blocks x 64 rows
  int row0 = blk * 64;
  int b = row0 >> 10, n0 = row0 & 1023;

  // ---- phase 1: refine + inline gather + score contribution, 4 rows per wave
  double dsum = 0.0;
  for (int j = 0; j < 4; ++j) {
    int rl  = wv * 4 + j;
    int row = row0 + rl;
    u64 e = top2[(size_t)lane * 16384 + row];    // lane = code-tile
    unsigned hi = (unsigned)(e >> 32), lo = (unsigned)e;
    unsigned mx = hi;
#pragma unroll
    for (int d = 1; d < 64; d <<= 1) mx = umax32(mx, __shfl_xor(mx, d));
    float fm = __uint_as_float(mx & 0xFFFFFF80u);
    float th = fm - MARGIN_ACC;
    bool c0 = __uint_as_float(hi & 0xFFFFFF80u) >= th;
    bool c1 = __uint_as_float(lo & 0xFFFFFF80u) >= th;
    u64 bal0 = __ballot(c0), bal1 = __ballot(c1);
    int kbest;
    double d2c;                                  // = ||e||^2 - 2 x.e for the chosen code
    if (__popcll(bal0) + __popcll(bal1) <= 1) {
      int l0 = __ffsll((unsigned long long)__ballot(hi == mx)) - 1;
      kbest = l0 * 128 + (int)(__shfl(hi, l0) & 127u);
      d2c = 64.0 - 2.0 * (double)fm;             // quantized acc: +4.9e-4 worst-case per row
    } else {
      const float* xr = x + (size_t)b * 262144 + (row & 1023);
      float4v ex;
#pragma unroll
      for (int i = 0; i < 4; ++i) ex[i] = xr[(size_t)(lane * 4 + i) * 1024];
      double bs = 1e300; int bk = 0x7fffffff;
      for (int pass = 0; pass < 2; ++pass) {
        u64 bal = pass ? bal1 : bal0;
        unsigned src = pass ? lo : hi;
        while (bal) {
          int l = __ffsll((unsigned long long)bal) - 1;
          bal &= bal - 1;
          int kc = l * 128 + (int)(__shfl(src, l) & 127u);
          float4v wv4 = *(const float4v*)&w[(size_t)kc * DIM + lane * 4];
          double s = 0.0;
#pragma unroll
          for (int i = 0; i < 4; ++i) { double ev = (double)wv4[i]; s += ev * (ev - 2.0 * (double)ex[i]); }
#pragma unroll
          for (int d = 1; d < 64; d <<= 1) s += __shfl_xor(s, d);
          if (s < bs || (s == bs && kc < bk)) { bs = s; bk = kc; }
        }
      }
      kbest = bk;                                // all lanes agree (shuffle-reduced)
      d2c = bs;                                  // exact fp64
    }
    if (lane == 0) { out[CODE_OFF + row] = (float)kbest; dsum += d2c; }
    // inline gather: whole wave loads this row's e-vector (coalesced 256B x4)
    const float* wrow = w + (size_t)kbest * 256;
#pragma unroll
    for (int i = 0; i < 4; ++i) ect[(i * 64 + lane) * 65 + rl] = wrow[i * 64 + lane];
  }
  __syncthreads();

  // ---- phase 2: write xq (full-wave 256B txns); loss from scores, no x read
  const size_t base = (size_t)b * 262144 + n0 + lane;
  for (int j = 0; j < 16; ++j) {
    int c = wv * 16 + j;
    out[base + (size_t)c * 1024] = ect[c * 65 + lane];
  }
  if (lane == 0) dpart[wv] = dsum;
  __syncthreads();
  if (t == 0) {
    double s = 0.0;
#pragma unroll
    for (int i = 0; i < 16; ++i) s += dpart[i];
    atomicAdd(&dacc[0], s);
    __threadfence();
    oldc = atomicAdd(cnt, 1u);
  }
  __syncthreads();
  if (oldc == 255u && t < 64) {                  // last block: wave 0 finalizes
    float ps = 0.f;
#pragma unroll
    for (int i = 0; i < 8; ++i) ps += sxxp[t * 8 + i];
#pragma unroll
    for (int d = 32; d; d >>= 1) ps += __shfl_xor(ps, d);
    if (t == 0) {
      __threadfence();
      double sd2 = *(volatile double*)&dacc[0];
      out[LOSS_OFF] = (float)(1.25 * ((double)ps + sd2) / 4194304.0);
    }
  }
}

// ---------------------------------------------------------------- launch
extern "C" void kernel_launch(void* const* d_in, const int* in_sizes, int n_in,
                              void* d_out, int out_size, void* d_ws, size_t ws_size,
                              hipStream_t stream) {
  const float* x = (const float*)d_in[0];
  const float* w = (const float*)d_in[1];
  float* out = (float*)d_out;
  char* ws = (char*)d_ws;
  _Float16* xh   = (_Float16*)(ws);                 //  8,388,608 B (swizzled tiles)
  _Float16* eh   = (_Float16*)(ws + 8388608);       //  4,194,304 B (swizzled tiles)
  float*    en2c = (float*)(ws + 12582912);         //     32,768 B
  u64*      top2 = (u64*)(ws + 12615680);           //  8,388,608 B ([64 tile][16384 row] u64)
  float*    sxxp = (float*)(ws + 21004288);         //      2,048 B (512 partials)
  double*   dacc = (double*)(ws + 21006336);        //          8 B (sum d2)
  unsigned* cnt  = (unsigned*)(ws + 21006344);      //          4 B

  k_prep<<<768, 256, 0, stream>>>(x, xh, w, eh, en2c, sxxp, dacc, cnt);
  k_gemm<<<256, 512, 0, stream>>>(xh, eh, en2c, top2);
  k_out<<<256, 1024, 0, stream>>>(top2, x, w, out, sxxp, dacc, cnt);
}

// Round 7
// 174.712 us; speedup vs baseline: 5.3096x; 1.1501x over previous
//
#include <hip/hip_runtime.h>
#include <hip/hip_bf16.h>

// Problem: x (16,256,32,32) fp32, weight (8193,256) fp32 (emb = first 8192 rows).
// Rows: r = b*1024 + (h*32+w), xf[r][c] = x[b*262144 + c*1024 + (r&1023)].
// Outputs (flat fp32): xq (4194304) | loss (1) | code-as-float (16384).
//
// R16: revert to the verified R9 structure (171.3us, k_gemm 88.6us) after
// R10-R15 structural rewrites all regressed or raced (R15 failed correctness:
// sporadic top2 corruption under the single-barrier ring scheme - a sync-
// structure race I could not isolate; m152 lesson). Only retained delta vs R9:
// R11's float2-vectorized k_prep x-path (8B/lane, G13), which passed
// correctness in R11 with this exact 64-half swizzled layout.
// k_gemm: R9 verbatim (128^2 tile, BK=64 chunks, 2-barrier loop, gll16
// staging, swizzled LDS, register top-2 epilogue + LDS merge).
// k_out: R9 verbatim.

#define N_ROWS   16384
#define KCODES   8192
#define DIM      256
#define LOSS_OFF 4194304
#define CODE_OFF 4194305
#define MARGIN_ACC 0.006f          // covers f16 noise (~8e-4 rms) + 4.9e-4 idx-mask quant

typedef _Float16 half8  __attribute__((ext_vector_type(8)));
typedef _Float16 half4v __attribute__((ext_vector_type(4)));
typedef float    float4v __attribute__((ext_vector_type(4)));
typedef float    float2v __attribute__((ext_vector_type(2)));
typedef unsigned long long u64;

__device__ __forceinline__ unsigned umax32(unsigned a, unsigned b) { return a > b ? a : b; }
__device__ __forceinline__ unsigned umin32(unsigned a, unsigned b) { return a < b ? a : b; }
__device__ __forceinline__ void gll16(const _Float16* g, _Float16* l) {
  __builtin_amdgcn_global_load_lds((const __attribute__((address_space(1))) void*)g,
                                   (__attribute__((address_space(3))) void*)l, 16, 0, 0);
}

// Swizzled tile layout (xh and eh): per 128-row tile, per 64-half K-chunk,
// 16B unit u = row_local*8 + (kgrp ^ (row_local & 7)); chunk = 8192 halves.

// ---------------------------------------------------------------- fused prep (+ Sxx partials)
__global__ __launch_bounds__(256) void k_prep(const float* __restrict__ x, _Float16* __restrict__ xh,
                                              const float* __restrict__ wt, _Float16* __restrict__ eh,
                                              float* __restrict__ en2c, float* __restrict__ sxxp,
                                              double* __restrict__ dacc, unsigned* __restrict__ cnt) {
  __shared__ float lsx[128 * 65];               // x path: [n][c'] fp32, stride 65
  __shared__ __align__(16) _Float16 ls[8192];   // e path: 32 codes x 256 halves
  __shared__ float es[32];
  int t = threadIdx.x;
  int lane = t & 63, wv = t >> 6;
  int bid = blockIdx.x;
  if (bid < 512) {
    // ---- x path: 512 blocks = 128 row-tiles x 4 K-chunks
    if (bid == 0 && t == 0) { dacc[0] = 0.0; *cnt = 0u; }   // consumed only in k_out
    int blk = bid >> 2, cc = bid & 3;
    int row0 = blk * 128;
    int b    = row0 >> 10;
    int n0   = row0 & 1023;
    const float* xb = x + (size_t)b * 262144 + n0;   // xb[c*1024 + n_local]
    int c_off = t >> 6;                              // 0..3 (one c per wave per j)
    int nn    = (t & 63) * 2;                        // 0..126
    float sxx = 0.f;
    for (int j = 0; j < 16; ++j) {
      int c = cc * 64 + j * 4 + c_off;
      float2v v = *(const float2v*)&xb[(size_t)c * 1024 + nn];   // wave: 512B contiguous
      int cp = c & 63;
      sxx = fmaf(v[0], v[0], sxx);
      sxx = fmaf(v[1], v[1], sxx);
      lsx[nn * 65 + cp]       = v[0];               // 2-way bank alias (free)
      lsx[(nn + 1) * 65 + cp] = v[1];
    }
    __syncthreads();
#pragma unroll
    for (int i = 0; i < 4; ++i) {                    // 1024 units = 128 rows x 8
      int unit = i * 256 + t;
      int rl = unit >> 3, p = unit & 7;
      const float* src = &lsx[rl * 65 + p * 8];
      half8 h;
#pragma unroll
      for (int k2 = 0; k2 < 8; ++k2) h[k2] = (_Float16)src[k2];
      int p7 = p ^ (rl & 7);
      *(half8*)&xh[(size_t)blk * 32768 + (size_t)cc * 8192 + (size_t)rl * 64 + p7 * 8] = h;
    }
#pragma unroll
    for (int d = 32; d; d >>= 1) sxx += __shfl_xor(sxx, d);
    __syncthreads();
    if (lane == 0) lsx[wv] = sxx;
    __syncthreads();
    if (t == 0) sxxp[bid] = lsx[0] + lsx[1] + lsx[2] + lsx[3];
  } else {
    // ---- e path: 256 blocks x 32 codes (swizzled eh)
    int blk  = bid - 512;
    int k0 = blk * 32;
    const float* wb = wt + (size_t)k0 * 256;
    for (int i = 0; i < 8; ++i) {
      int lin = i * 1024 + t * 4;                 // all lanes of a wave share lin>>8 = i*4+wv
      float4v v = *(const float4v*)&wb[lin];
      half4v h; float ss = 0.f;
#pragma unroll
      for (int j = 0; j < 4; ++j) { h[j] = (_Float16)v[j]; ss = fmaf(v[j], v[j], ss); }
      *(half4v*)&ls[lin] = h;
#pragma unroll
      for (int d = 32; d; d >>= 1) ss += __shfl_xor(ss, d);
      if (lane == 0) es[i * 4 + wv] = ss;
    }
    __syncthreads();
    size_t tb = (size_t)(k0 >> 7) * 32768;
    for (int i = 0; i < 4; ++i) {
      int u = i * 256 + t;
      int code_l = u >> 5;
      int cu = u & 31, chunk = cu >> 3, p = cu & 7;
      int kgl = k0 + code_l;
      int kg = p ^ (kgl & 7);
      half8 h = *(half8*)&ls[code_l * 256 + chunk * 64 + kg * 8];
      *(half8*)&eh[tb + (size_t)chunk * 8192 + (size_t)(kgl & 127) * 64 + p * 8] = h;
    }
    if (t < 32) en2c[k0 + t] = 32.0f - 0.5f * es[t];
  }
}

// ---------------------------------------------------------------- main GEMM (A=codes, B=xrows) + top-2 epilogue [R9]
__global__ __launch_bounds__(256) void k_gemm(const _Float16* __restrict__ xh, const _Float16* __restrict__ eh,
                                              const float* __restrict__ en2c,
                                              u64* __restrict__ top2) {
  __shared__ __align__(16) _Float16 As[8192];   // 128 codes x 64 halves (swizzled)
  __shared__ __align__(16) _Float16 Bs[8192];   // 128 xrows x 64 halves (swizzled)
  int t    = threadIdx.x;
  int bx   = blockIdx.x;   // code tile 0..63 (128 codes)
  int by   = blockIdx.y;   // xrow tile 0..127 (128 rows)
  int lane = t & 63, w = t >> 6;
  int wr = w & 1, wc = w >> 1;                  // wave: codes 64*wr, xrows 64*wc
  int ln15 = lane & 15, q = lane >> 4;
  int q4 = q * 4;

  const _Float16* Ag = eh + (size_t)bx * 32768;
  const _Float16* Bg = xh + (size_t)by * 32768;

  int kwave = bx * 128 + wr * 64;
  float4v cin[4];
#pragma unroll
  for (int mi = 0; mi < 4; ++mi) cin[mi] = *(const float4v*)&en2c[kwave + mi * 16 + q4];

  float4v acc[4][4];
#pragma unroll
  for (int mi = 0; mi < 4; ++mi)
#pragma unroll
    for (int ni = 0; ni < 4; ++ni) acc[mi][ni] = cin[mi];

  int so = (w * 64 + lane) * 8;                 // staging source offset (halves)
  int lo = w * 512;                             // per-wave LDS dest offset (halves)

  for (int ch = 0; ch < 4; ++ch) {
    if (ch) __syncthreads();
    const _Float16* ac = Ag + ch * 8192;
    const _Float16* bc = Bg + ch * 8192;
#pragma unroll
    for (int i = 0; i < 4; ++i) {
      gll16(ac + i * 2048 + so, As + i * 2048 + lo);
      gll16(bc + i * 2048 + so, Bs + i * 2048 + lo);
    }
    __syncthreads();
#pragma unroll
    for (int ks = 0; ks < 2; ++ks) {
      half8 af[4], bf[4];
#pragma unroll
      for (int mi = 0; mi < 4; ++mi) {
        int row = wr * 64 + mi * 16 + ln15;     // code row
        af[mi] = *(const half8*)&As[(row * 8 + ((ks * 4 + q) ^ (row & 7))) * 8];
      }
#pragma unroll
      for (int ni = 0; ni < 4; ++ni) {
        int row = wc * 64 + ni * 16 + ln15;     // xrow
        bf[ni] = *(const half8*)&Bs[(row * 8 + ((ks * 4 + q) ^ (row & 7))) * 8];
      }
#pragma unroll
      for (int mi = 0; mi < 4; ++mi)
#pragma unroll
        for (int ni = 0; ni < 4; ++ni)
          acc[mi][ni] = __builtin_amdgcn_mfma_f32_16x16x32_f16(af[mi], bf[ni], acc[mi][ni], 0, 0, 0);
    }
  }

  // epilogue: per x-row top-2 (max of biased acc) over this wave's 64 codes.
  __syncthreads();                              // frag reads done; reuse As
  u64* ep = (u64*)(void*)As;                    // [128 xrows][2 wr]
  int ibase = wr * 64 + q4;

#pragma unroll
  for (int ni = 0; ni < 4; ++ni) {
    unsigned hi[8], lo2[8];
#pragma unroll
    for (int j = 0; j < 8; ++j) {
      int mi = j >> 1, rb = (j & 1) * 2;
      unsigned p0 = (__float_as_uint(acc[mi][ni][rb])     & 0xFFFFFF80u) | (unsigned)(ibase + mi * 16 + rb);
      unsigned p1 = (__float_as_uint(acc[mi][ni][rb + 1]) & 0xFFFFFF80u) | (unsigned)(ibase + mi * 16 + rb + 1);
      hi[j] = umax32(p0, p1); lo2[j] = umin32(p0, p1);
    }
#pragma unroll
    for (int st = 4; st; st >>= 1)
#pragma unroll
      for (int j = 0; j < 8; ++j) if (j < st) {
        unsigned nb = umax32(hi[j], hi[j + st]);
        unsigned ns = umax32(umin32(hi[j], hi[j + st]), umax32(lo2[j], lo2[j + st]));
        hi[j] = nb; lo2[j] = ns;
      }
    unsigned b = hi[0], s = lo2[0];
#pragma unroll
    for (int d = 16; d < 64; d <<= 1) {
      unsigned ob = __shfl_xor(b, d);
      unsigned os = __shfl_xor(s, d);
      unsigned ns = umax32(umin32(b, ob), umax32(s, os));
      b = umax32(b, ob); s = ns;
    }
    if (q == 0) {
      int rl = wc * 64 + ni * 16 + ln15;
      ep[rl * 2 + wr] = ((u64)b << 32) | s;
    }
  }
  __syncthreads();
  if (t < 128) {
    u64 A = ep[t * 2 + 0], B = ep[t * 2 + 1];
    unsigned a0 = (unsigned)(A >> 32), a1 = (unsigned)A;
    unsigned b0 = (unsigned)(B >> 32), b1 = (unsigned)B;
    unsigned best = umax32(a0, b0);
    unsigned sec  = umax32(umin32(a0, b0), umax32(a1, b1));
    top2[(size_t)bx * 16384 + (size_t)by * 128 + t] = ((u64)best << 32) | sec;
  }
}

// ---------------------------------------------------------------- fused refine + gather + loss
__global__ __launch_bounds__(1024) void k_out(const u64* __restrict__ top2,
                                              const float* __restrict__ x, const float* __restrict__ w,
                                              float* __restrict__ out, const float* __restrict__ sxxp,
                                              double* __restrict__ dacc, unsigned* __restrict__ cnt) {
  __shared__ float ect[256 * 65];      // [c][r] transposed, stride 65; both phases <=2-way
  __shared__ double dpart[16];
  __shared__ unsigned oldc;
  int t    = threadIdx.x;
  int lane = t & 63, wv = t >> 6;      // 16 waves
  int blk  = blockIdx.x;               // 256 blocks x 64 rows
  int row0 = blk * 64;
  int b = row0 >> 10, n0 = row0 & 1023;

  // ---- phase 1: refine + inline gather + score contribution, 4 rows per wave
  double dsum = 0.0;
  for (int j = 0; j < 4; ++j) {
    int rl  = wv * 4 + j;
    int row = row0 + rl;
    u64 e = top2[(size_t)lane * 16384 + row];    // lane = code-tile
    unsigned hi = (unsigned)(e >> 32), lo = (unsigned)e;
    unsigned mx = hi;
#pragma unroll
    for (int d = 1; d < 64; d <<= 1) mx = umax32(mx, __shfl_xor(mx, d));
    float fm = __uint_as_float(mx & 0xFFFFFF80u);
    float th = fm - MARGIN_ACC;
    bool c0 = __uint_as_float(hi & 0xFFFFFF80u) >= th;
    bool c1 = __uint_as_float(lo & 0xFFFFFF80u) >= th;
    u64 bal0 = __ballot(c0), bal1 = __ballot(c1);
    int kbest;
    double d2c;                                  // = ||e||^2 - 2 x.e for the chosen code
    if (__popcll(bal0) + __popcll(bal1) <= 1) {
      int l0 = __ffsll((unsigned long long)__ballot(hi == mx)) - 1;
      kbest = l0 * 128 + (int)(__shfl(hi, l0) & 127u);
      d2c = 64.0 - 2.0 * (double)fm;             // quantized acc: +4.9e-4 worst-case per row
    } else {
      const float* xr = x + (size_t)b * 262144 + (row & 1023);
      float4v ex;
#pragma unroll
      for (int i = 0; i < 4; ++i) ex[i] = xr[(size_t)(lane * 4 + i) * 1024];
      double bs = 1e300; int bk = 0x7fffffff;
      for (int pass = 0; pass < 2; ++pass) {
        u64 bal = pass ? bal1 : bal0;
        unsigned src = pass ? lo : hi;
        while (bal) {
          int l = __ffsll((unsigned long long)bal) - 1;
          bal &= bal - 1;
          int kc = l * 128 + (int)(__shfl(src, l) & 127u);
          float4v wv4 = *(const float4v*)&w[(size_t)kc * DIM + lane * 4];
          double s = 0.0;
#pragma unroll
          for (int i = 0; i < 4; ++i) { double ev = (double)wv4[i]; s += ev * (ev - 2.0 * (double)ex[i]); }
#pragma unroll
          for (int d = 1; d < 64; d <<= 1) s += __shfl_xor(s, d);
          if (s < bs || (s == bs && kc < bk)) { bs = s; bk = kc; }
        }
      }
      kbest = bk;                                // all lanes agree (shuffle-reduced)
      d2c = bs;                                  // exact fp64
    }
    if (lane == 0) { out[CODE_OFF + row] = (float)kbest; dsum += d2c; }
    // inline gather: whole wave loads this row's e-vector (coalesced 256B x4)
    const float* wrow = w + (size_t)kbest * 256;
#pragma unroll
    for (int i = 0; i < 4; ++i) ect[(i * 64 + lane) * 65 + rl] = wrow[i * 64 + lane];
  }
  __syncthreads();

  // ---- phase 2: write xq (full-wave 256B txns); loss from scores, no x read
  const size_t base = (size_t)b * 262144 + n0 + lane;
  for (int j = 0; j < 16; ++j) {
    int c = wv * 16 + j;
    out[base + (size_t)c * 1024] = ect[c * 65 + lane];
  }
  if (lane == 0) dpart[wv] = dsum;
  __syncthreads();
  if (t == 0) {
    double s = 0.0;
#pragma unroll
    for (int i = 0; i < 16; ++i) s += dpart[i];
    atomicAdd(&dacc[0], s);
    __threadfence();
    oldc = atomicAdd(cnt, 1u);
  }
  __syncthreads();
  if (oldc == 255u && t < 64) {                  // last block: wave 0 finalizes
    float ps = 0.f;
#pragma unroll
    for (int i = 0; i < 8; ++i) ps += sxxp[t * 8 + i];
#pragma unroll
    for (int d = 32; d; d >>= 1) ps += __shfl_xor(ps, d);
    if (t == 0) {
      __threadfence();
      double sd2 = *(volatile double*)&dacc[0];
      out[LOSS_OFF] = (float)(1.25 * ((double)ps + sd2) / 4194304.0);
    }
  }
}

// ---------------------------------------------------------------- launch
extern "C" void kernel_launch(void* const* d_in, const int* in_sizes, int n_in,
                              void* d_out, int out_size, void* d_ws, size_t ws_size,
                              hipStream_t stream) {
  const float* x = (const float*)d_in[0];
  const float* w = (const float*)d_in[1];
  float* out = (float*)d_out;
  char* ws = (char*)d_ws;
  _Float16* xh   = (_Float16*)(ws);                 //  8,388,608 B (swizzled tiles)
  _Float16* eh   = (_Float16*)(ws + 8388608);       //  4,194,304 B (swizzled tiles)
  float*    en2c = (float*)(ws + 12582912);         //     32,768 B
  u64*      top2 = (u64*)(ws + 12615680);           //  8,388,608 B ([64 bx][16384 row] u64)
  float*    sxxp = (float*)(ws + 21004288);         //      2,048 B (512 partials)
  double*   dacc = (double*)(ws + 21006336);        //          8 B (sum d2)
  unsigned* cnt  = (unsigned*)(ws + 21006344);      //          4 B

  k_prep<<<768, 256, 0, stream>>>(x, xh, w, eh, en2c, sxxp, dacc, cnt);
  k_gemm<<<dim3(64, 128), 256, 0, stream>>>(xh, eh, en2c, top2);
  k_out<<<256, 1024, 0, stream>>>(top2, x, w, out, sxxp, dacc, cnt);
}